// Round 2
// baseline (2169.123 us; speedup 1.0000x reference)
//
#include <hip/hip_runtime.h>
#include <hip/hip_bf16.h>
#include <math.h>

typedef __hip_bfloat16 bf16;

#define BB 4096
#define LL 8
#define NN 9
#define SS 877
#define DD 256
#define D2 512
#define TT 137
#define HH 128
#define MM (BB*NN)   // 36864

__device__ __forceinline__ float b2f(bf16 v){ return __bfloat162float(v); }
__device__ __forceinline__ float lrelu(float x){ return x > 0.f ? x : 0.01f*x; }
__device__ __forceinline__ float gelu_tanh(float x){
    float x3 = x*x*x;
    float t = tanhf(0.7978845608028654f*(x + 0.044715f*x3));
    return 0.5f*x*(1.f + t);
}

// -------- dtype detect: 1 = bf16, 0 = f32 ------------------------------------
// If data is bf16, even-index 16-bit halves are real values (~N(0,1)) -> in range.
// If data is f32, even-index halves are low mantissa bits -> random exponent,
// only ~9% land in (1e-4, 100).
__global__ __launch_bounds__(256) void k_detect(const unsigned short* __restrict__ p,
                                                int* __restrict__ flag){
    int t = threadIdx.x;
    int cnt = 0;
    for (int k = t; k < 2048; k += 256){
        unsigned int bits = (unsigned int)p[2*k] << 16;
        float v = __uint_as_float(bits);
        float a = fabsf(v);
        if (v == 0.f || (a > 1e-4f && a < 100.f)) cnt++;
    }
    __shared__ int red[256];
    red[t] = cnt; __syncthreads();
    for (int s = 128; s > 0; s >>= 1){ if (t < s) red[t] += red[t+s]; __syncthreads(); }
    if (t == 0) *flag = (red[0] > 1024) ? 1 : 0;
}

// -------- convert a tensor to f32 (bf16 or f32 source, per flag) -------------
__global__ __launch_bounds__(256) void k_cvt(const void* __restrict__ in,
                                             float* __restrict__ out, int n,
                                             const int* __restrict__ dflag){
    int isb = *dflag;
    for (int i = blockIdx.x*blockDim.x + threadIdx.x; i < n; i += gridDim.x*blockDim.x)
        out[i] = isb ? b2f(((const bf16*)in)[i]) : ((const float*)in)[i];
}

// ---------------- valid mask ----------------
__global__ __launch_bounds__(256) void k_valid(const void* __restrict__ src,
                                               const void* __restrict__ srcn,
                                               const int* __restrict__ dflag,
                                               float* __restrict__ vm){
    int isb = *dflag;
    int m = blockIdx.x; int b = m / NN, n = m % NN;
    const bf16* rh; const float* rf;
    if (n == 0){ size_t o = (size_t)b*SS; rh = (const bf16*)src + o; rf = (const float*)src + o; }
    else       { size_t o = ((size_t)b*LL + (n-1))*SS; rh = (const bf16*)srcn + o; rf = (const float*)srcn + o; }
    float s = 0.f;
    for (int i = threadIdx.x; i < SS; i += 256) s += fabsf(isb ? b2f(rh[i]) : rf[i]);
    __shared__ float red[256];
    red[threadIdx.x] = s; __syncthreads();
    for (int st = 128; st > 0; st >>= 1){
        if (threadIdx.x < st) red[threadIdx.x] += red[threadIdx.x + st];
        __syncthreads();
    }
    if (threadIdx.x == 0) vm[m] = (red[0] > 0.f) ? 1.f : 0.f;
}

// -------- GEMM1: x(M,877) @ enc_w1(877,512) + bias -> bn1 -> leaky -----------
__global__ __launch_bounds__(256) void k_gemm1(const void* __restrict__ src,
                                               const void* __restrict__ srcn,
                                               const int* __restrict__ dflag,
                                               const float* __restrict__ W,
                                               const float* __restrict__ bias,
                                               const float* __restrict__ bng,
                                               const float* __restrict__ bnb,
                                               float* __restrict__ out){
    __shared__ float As[64][17];
    __shared__ float Bs[16][68];
    int isb = *dflag;
    int row0 = blockIdx.x*64, col0 = blockIdx.y*64;
    int tid = threadIdx.x;
    int tr = tid/16, tc = tid%16;
    float acc[4][4] = {};

    int ar  = tid >> 2;
    int ac0 = (tid & 3) * 4;
    int m_a = row0 + ar;
    int b_a = m_a / NN, n_a = m_a % NN;
    const bf16* ah; const float* af;
    if (n_a == 0){ size_t o = (size_t)b_a*SS; ah = (const bf16*)src + o; af = (const float*)src + o; }
    else         { size_t o = ((size_t)b_a*LL + (n_a-1))*SS; ah = (const bf16*)srcn + o; af = (const float*)srcn + o; }
    int br  = tid >> 4;
    int bc0 = (tid & 15) * 4;

    for (int k0 = 0; k0 < SS; k0 += 16){
        #pragma unroll
        for (int e = 0; e < 4; e++){
            int kk = k0 + ac0 + e;
            As[ar][ac0+e] = (kk < SS) ? (isb ? b2f(ah[kk]) : af[kk]) : 0.f;
        }
        int kb = k0 + br;
        #pragma unroll
        for (int e = 0; e < 4; e++){
            Bs[br][bc0+e] = (kb < SS) ? W[(size_t)kb*D2 + col0 + bc0 + e] : 0.f;
        }
        __syncthreads();
        #pragma unroll
        for (int kk = 0; kk < 16; kk++){
            float a[4], bv[4];
            #pragma unroll
            for (int i = 0; i < 4; i++) a[i] = As[tr*4+i][kk];
            #pragma unroll
            for (int j = 0; j < 4; j++) bv[j] = Bs[kk][tc*4+j];
            #pragma unroll
            for (int i = 0; i < 4; i++)
                #pragma unroll
                for (int j = 0; j < 4; j++) acc[i][j] += a[i]*bv[j];
        }
        __syncthreads();
    }
    const float inv = rsqrtf(1.f + 1e-5f);
    for (int i = 0; i < 4; i++){
        int m = row0 + tr*4 + i;
        for (int j = 0; j < 4; j++){
            int c = col0 + tc*4 + j;
            float y = (acc[i][j] + bias[c]) * (bng[c]*inv) + bnb[c];
            out[(size_t)m*D2 + c] = lrelu(y);
        }
    }
}

// -------- generic GEMM: A f32 @ W f32 (K x Nc), fused epilogues --------------
#define EPI_NONE 0
#define EPI_BN_LEAKY 1
#define EPI_RES 2
#define EPI_GELU 3

__global__ __launch_bounds__(256) void k_gemm(const float* __restrict__ A, int a_rstride,
                                              const float* __restrict__ W, int Nc, int K,
                                              const float* __restrict__ bias,
                                              const float* __restrict__ bng,
                                              const float* __restrict__ bnb,
                                              const float* __restrict__ res, int res_stride,
                                              int mode, float* __restrict__ out, int ldo){
    __shared__ float As[64][17];
    __shared__ float Bs[16][68];
    int row0 = blockIdx.x*64, col0 = blockIdx.y*64;
    int tid = threadIdx.x;
    int tr = tid/16, tc = tid%16;
    float acc[4][4] = {};

    int ar  = tid >> 2;
    int ac0 = (tid & 3) * 4;
    const float* arow = A + (size_t)(row0 + ar)*a_rstride;
    int br  = tid >> 4;
    int bc0 = (tid & 15) * 4;

    for (int k0 = 0; k0 < K; k0 += 16){
        #pragma unroll
        for (int e = 0; e < 4; e++) As[ar][ac0+e] = arow[k0 + ac0 + e];
        #pragma unroll
        for (int e = 0; e < 4; e++)
            Bs[br][bc0+e] = W[(size_t)(k0+br)*Nc + col0 + bc0 + e];
        __syncthreads();
        #pragma unroll
        for (int kk = 0; kk < 16; kk++){
            float a[4], bv[4];
            #pragma unroll
            for (int i = 0; i < 4; i++) a[i] = As[tr*4+i][kk];
            #pragma unroll
            for (int j = 0; j < 4; j++) bv[j] = Bs[kk][tc*4+j];
            #pragma unroll
            for (int i = 0; i < 4; i++)
                #pragma unroll
                for (int j = 0; j < 4; j++) acc[i][j] += a[i]*bv[j];
        }
        __syncthreads();
    }
    const float inv = rsqrtf(1.f + 1e-5f);
    for (int i = 0; i < 4; i++){
        int m = row0 + tr*4 + i;
        for (int j = 0; j < 4; j++){
            int c = col0 + tc*4 + j;
            float y = acc[i][j] + (bias ? bias[c] : 0.f);
            if (mode == EPI_BN_LEAKY){
                y = y * (bng[c]*inv) + bnb[c];
                y = lrelu(y);
            } else if (mode == EPI_RES){
                y += res[(size_t)m*res_stride + c];
            } else if (mode == EPI_GELU){
                y = gelu_tanh(y);
            }
            out[(size_t)m*ldo + c] = y;
        }
    }
}

// ---------------- role + class tokens epilogue ----------------
__global__ __launch_bounds__(256) void k_rolecls(const float* __restrict__ tokc,
                                                 const float* __restrict__ tokn1,
                                                 const float* __restrict__ tokn2,
                                                 const float* __restrict__ cell_tokens,
                                                 const float* __restrict__ cell_inf,
                                                 const float* __restrict__ vm,
                                                 float* __restrict__ fo){
    int m = blockIdx.x, d = threadIdx.x;
    int n = m % NN;
    float v = vm[m];
    const float* role = (n == 0) ? tokc : (n <= 4 ? tokn1 : tokn2);
    float cl = 0.f;
    #pragma unroll
    for (int c = 0; c < 13; c++)
        cl += cell_inf[(size_t)m*13 + c] * cell_tokens[c*DD + d];
    fo[(size_t)m*DD + d] += (role[d] + cl) * v;
}

// ---------------- block reductions for LN ----------------
__device__ __forceinline__ float blksum(float v, float* red){
    int t = threadIdx.x;
    red[t] = v; __syncthreads();
    for (int s = 128; s > 0; s >>= 1){
        if (t < s) red[t] += red[t+s];
        __syncthreads();
    }
    float r = red[0]; __syncthreads();
    return r;
}

__global__ __launch_bounds__(256) void k_lnchain(const float* __restrict__ in,
                                                 const float* __restrict__ g1, const float* __restrict__ b1,
                                                 const float* __restrict__ g2, const float* __restrict__ b2,
                                                 float* __restrict__ fo1, float* __restrict__ hn){
    __shared__ float red[256];
    int m = blockIdx.x, d = threadIdx.x;
    float x = in[(size_t)m*DD + d];
    float mu = blksum(x, red) * (1.f/256.f);
    float dx = x - mu;
    float var = blksum(dx*dx, red) * (1.f/256.f);
    float y = dx * rsqrtf(var + 1e-5f) * g1[d] + b1[d];
    y = fmaxf(y, 0.f);
    fo1[(size_t)m*DD + d] = y;
    float mu2 = blksum(y, red) * (1.f/256.f);
    float dy = y - mu2;
    float var2 = blksum(dy*dy, red) * (1.f/256.f);
    hn[(size_t)m*DD + d] = dy * rsqrtf(var2 + 1e-5f) * g2[d] + b2[d];
}

__global__ __launch_bounds__(256) void k_ln(const float* __restrict__ in,
                                            const float* __restrict__ g, const float* __restrict__ b,
                                            float* __restrict__ out){
    __shared__ float red[256];
    int m = blockIdx.x, d = threadIdx.x;
    float x = in[(size_t)m*DD + d];
    float mu = blksum(x, red) * (1.f/256.f);
    float dx = x - mu;
    float var = blksum(dx*dx, red) * (1.f/256.f);
    out[(size_t)m*DD + d] = dx * rsqrtf(var + 1e-5f) * g[d] + b[d];
}

// ---------------- attention (only query token 0 needed) ----------------
__global__ __launch_bounds__(256) void k_attn(const float* __restrict__ q,
                                              const float* __restrict__ k,
                                              const float* __restrict__ v,
                                              const float* __restrict__ vm,
                                              float* __restrict__ o){
    int b = blockIdx.x, t = threadIdx.x;
    __shared__ float ks[NN][DD];
    __shared__ float vs[NN][DD];
    __shared__ float qs[DD];
    __shared__ float sc[4][NN];
    __shared__ float val[NN];
    qs[t] = q[(size_t)b*DD + t];
    for (int j = 0; j < NN; j++){
        ks[j][t] = k[((size_t)b*NN + j)*DD + t];
        vs[j][t] = v[((size_t)b*NN + j)*DD + t];
    }
    if (t < NN) val[t] = vm[b*NN + t];
    __syncthreads();
    if (t < 4*NN){
        int h = t / NN, j = t % NN;
        float s = 0.f;
        for (int d = 0; d < 64; d++) s += qs[h*64+d] * ks[j][h*64+d];
        s *= 0.125f;
        if (!(val[j] > 0.f)) s = -1e9f;
        sc[h][j] = s;
    }
    __syncthreads();
    if (t < 4){
        float mx = -1e30f;
        for (int j = 0; j < NN; j++) mx = fmaxf(mx, sc[t][j]);
        float den = 0.f;
        for (int j = 0; j < NN; j++){ float e = expf(sc[t][j]-mx); sc[t][j] = e; den += e; }
        float iv = 1.f/den;
        for (int j = 0; j < NN; j++) sc[t][j] *= iv;
    }
    __syncthreads();
    int h = t >> 6;
    float acc = 0.f;
    for (int j = 0; j < NN; j++) acc += sc[h][j] * vs[j][t];
    o[(size_t)b*DD + t] = acc;
}

// ---------------- pred head ----------------
__global__ __launch_bounds__(256) void k_pred(const float* __restrict__ feat,
                                              const float* __restrict__ w1,
                                              const float* __restrict__ b1,
                                              const float* __restrict__ bg,
                                              const float* __restrict__ bb,
                                              const float* __restrict__ w2,
                                              const int* __restrict__ dflag,
                                              void* __restrict__ out){
    int isb = *dflag;
    int ti = blockIdx.y;
    int brow0 = blockIdx.x*64;
    int tid = threadIdx.x;
    __shared__ float fs[64][33];
    __shared__ float wsh[32][HH];
    __shared__ float red[64][33];
    int tx = tid & 31;
    int ty = tid >> 5;
    float acc[8][4] = {};
    for (int k0 = 0; k0 < DD; k0 += 32){
        #pragma unroll
        for (int e = 0; e < 8; e++){
            int l = tid*8 + e; int r = l >> 5, c = l & 31;
            fs[r][c] = feat[(size_t)(brow0+r)*DD + k0 + c];
        }
        #pragma unroll
        for (int e = 0; e < 16; e++){
            int l = tid*16 + e; int r = l >> 7, c = l & 127;
            wsh[r][c] = w1[((size_t)ti*DD + k0 + r)*HH + c];
        }
        __syncthreads();
        #pragma unroll
        for (int kk = 0; kk < 32; kk++){
            float wv[4];
            #pragma unroll
            for (int j = 0; j < 4; j++) wv[j] = wsh[kk][tx*4+j];
            #pragma unroll
            for (int i = 0; i < 8; i++){
                float a = fs[ty*8+i][kk];
                #pragma unroll
                for (int j = 0; j < 4; j++) acc[i][j] += a*wv[j];
            }
        }
        __syncthreads();
    }
    const float inv = rsqrtf(1.f + 1e-5f);
    float part[8];
    #pragma unroll
    for (int i = 0; i < 8; i++){
        float p = 0.f;
        #pragma unroll
        for (int j = 0; j < 4; j++){
            int hc = tx*4 + j;
            float y = (acc[i][j] + b1[ti*HH+hc]) * (bg[ti*HH+hc]*inv) + bb[ti*HH+hc];
            y = lrelu(y);
            p += y * w2[ti*HH+hc];
        }
        part[i] = p;
    }
    #pragma unroll
    for (int i = 0; i < 8; i++) red[ty*8+i][tx] = part[i];
    __syncthreads();
    if (tid < 64){
        float s = 0.f;
        for (int x = 0; x < 32; x++) s += red[tid][x];
        size_t oi = (size_t)(brow0+tid)*TT + ti;
        if (isb) ((bf16*)out)[oi] = __float2bfloat16(s);
        else     ((float*)out)[oi] = s;
    }
}

extern "C" void kernel_launch(void* const* d_in, const int* in_sizes, int n_in,
                              void* d_out, int out_size, void* d_ws, size_t ws_size,
                              hipStream_t stream) {
    float* ws = (float*)d_ws;
    int* dflag = (int*)d_ws;            // ws[0..15] reserved for flag
    dim3 blk(256);

    // dtype detect from `source`
    k_detect<<<1, blk, 0, stream>>>((const unsigned short*)d_in[0], dflag);

    // convert all weight-like tensors to f32 in ws
    float* cw = ws + 16;
    size_t co = 0;
    auto CV = [&](int idx, size_t n)->float*{
        float* dst = cw + co; co += n;
        int blocks = (int)((n + 1023) / 1024); if (blocks < 1) blocks = 1;
        k_cvt<<<blocks, blk, 0, stream>>>(d_in[idx], dst, (int)n, dflag);
        return dst;
    };
    float* c_cellinf = CV(2,  (size_t)BB*NN*13);
    float* c_encw1 = CV(3,  (size_t)SS*D2);
    float* c_encb1 = CV(4,  D2);
    float* c_bn1g  = CV(5,  D2);
    float* c_bn1b  = CV(6,  D2);
    float* c_encw2 = CV(7,  (size_t)D2*DD);
    float* c_encb2 = CV(8,  DD);
    float* c_bn2g  = CV(9,  DD);
    float* c_bn2b  = CV(10, DD);
    float* c_projw = CV(11, (size_t)DD*DD);
    float* c_projb = CV(12, DD);
    float* c_plng  = CV(13, DD);
    float* c_plnb  = CV(14, DD);
    float* c_alng  = CV(15, DD);
    float* c_alnb  = CV(16, DD);
    float* c_wq    = CV(17, (size_t)DD*DD);
    float* c_wk    = CV(18, (size_t)DD*DD);
    float* c_wv    = CV(19, (size_t)DD*DD);
    float* c_wo    = CV(20, (size_t)DD*DD);
    float* c_wob   = CV(21, DD);
    float* c_flng  = CV(22, DD);
    float* c_flnb  = CV(23, DD);
    float* c_ffw1  = CV(24, (size_t)DD*D2);
    float* c_ffb1  = CV(25, D2);
    float* c_ffw2  = CV(26, (size_t)D2*DD);
    float* c_ffb2  = CV(27, DD);
    float* c_tokc  = CV(28, DD);
    float* c_tokn1 = CV(29, DD);
    float* c_tokn2 = CV(30, DD);
    float* c_ctok  = CV(31, (size_t)13*DD);
    float* c_pw1   = CV(32, (size_t)TT*DD*HH);
    float* c_pb1   = CV(33, (size_t)TT*HH);
    float* c_pbg   = CV(34, (size_t)TT*HH);
    float* c_pbb   = CV(35, (size_t)TT*HH);
    float* c_pw2   = CV(36, (size_t)TT*HH);

    // activations
    size_t off = 16 + co;
    float* vm   = ws + off; off += MM;
    float* bigA = ws + off; off += (size_t)MM*D2;   // h1 -> t0 -> k|v
    float* fo   = ws + off; off += (size_t)MM*DD;   // fo -> fo1
    float* hn   = ws + off; off += (size_t)MM*DD;
    float* qb   = ws + off; off += (size_t)BB*DD;
    float* ob   = ws + off; off += (size_t)BB*DD;
    float* fo2  = ws + off; off += (size_t)BB*DD;
    float* hn2  = ws + off; off += (size_t)BB*DD;
    float* g1   = ws + off; off += (size_t)BB*D2;
    float* feat = ws + off; off += (size_t)BB*DD;

    k_valid<<<MM, blk, 0, stream>>>(d_in[0], d_in[1], dflag, vm);
    k_gemm1<<<dim3(MM/64, D2/64), blk, 0, stream>>>(d_in[0], d_in[1], dflag,
        c_encw1, c_encb1, c_bn1g, c_bn1b, bigA);
    k_gemm<<<dim3(MM/64, DD/64), blk, 0, stream>>>(bigA, D2, c_encw2, DD, D2,
        c_encb2, c_bn2g, c_bn2b, nullptr, 0, EPI_BN_LEAKY, fo, DD);
    k_rolecls<<<MM, blk, 0, stream>>>(c_tokc, c_tokn1, c_tokn2, c_ctok, c_cellinf, vm, fo);
    float* t0 = bigA;
    k_gemm<<<dim3(MM/64, DD/64), blk, 0, stream>>>(fo, DD, c_projw, DD, DD,
        c_projb, nullptr, nullptr, nullptr, 0, EPI_NONE, t0, DD);
    k_lnchain<<<MM, blk, 0, stream>>>(t0, c_plng, c_plnb, c_alng, c_alnb, fo, hn);
    float* kb = bigA;
    float* vb = bigA + (size_t)MM*DD;
    k_gemm<<<dim3(MM/64, DD/64), blk, 0, stream>>>(hn, DD, c_wk, DD, DD,
        nullptr, nullptr, nullptr, nullptr, 0, EPI_NONE, kb, DD);
    k_gemm<<<dim3(MM/64, DD/64), blk, 0, stream>>>(hn, DD, c_wv, DD, DD,
        nullptr, nullptr, nullptr, nullptr, 0, EPI_NONE, vb, DD);
    k_gemm<<<dim3(BB/64, DD/64), blk, 0, stream>>>(hn, NN*DD, c_wq, DD, DD,
        nullptr, nullptr, nullptr, nullptr, 0, EPI_NONE, qb, DD);
    k_attn<<<BB, blk, 0, stream>>>(qb, kb, vb, vm, ob);
    k_gemm<<<dim3(BB/64, DD/64), blk, 0, stream>>>(ob, DD, c_wo, DD, DD,
        c_wob, nullptr, nullptr, fo, NN*DD, EPI_RES, fo2, DD);
    k_ln<<<BB, blk, 0, stream>>>(fo2, c_flng, c_flnb, hn2);
    k_gemm<<<dim3(BB/64, D2/64), blk, 0, stream>>>(hn2, DD, c_ffw1, D2, DD,
        c_ffb1, nullptr, nullptr, nullptr, 0, EPI_GELU, g1, D2);
    k_gemm<<<dim3(BB/64, DD/64), blk, 0, stream>>>(g1, D2, c_ffw2, DD, D2,
        c_ffb2, nullptr, nullptr, fo2, DD, EPI_RES, feat, DD);
    k_pred<<<dim3(BB/64, TT), blk, 0, stream>>>(feat, c_pw1, c_pb1, c_pbg, c_pbb, c_pw2, dflag, d_out);
}

// Round 3
// 1006.416 us; speedup vs baseline: 2.1553x; 2.1553x over previous
//
#include <hip/hip_runtime.h>
#include <hip/hip_bf16.h>
#include <math.h>

typedef __hip_bfloat16 bf16;
typedef __attribute__((ext_vector_type(8))) short short8;
typedef __attribute__((ext_vector_type(4))) float f32x4;

#define BB 4096
#define LL 8
#define NN 9
#define SS 877
#define DD 256
#define D2 512
#define TT 137
#define HH 128
#define MM (BB*NN)   // 36864
#define KP1 896      // 877 padded to mult of 32

__device__ __forceinline__ float lrelu(float x){ return x > 0.f ? x : 0.01f*x; }
__device__ __forceinline__ float gelu_tanh(float x){
    float x3 = x*x*x;
    float t = tanhf(0.7978845608028654f*(x + 0.044715f*x3));
    return 0.5f*x*(1.f + t);
}
__device__ __forceinline__ short f2b(float x){
    union { bf16 h; short s; } u; u.h = __float2bfloat16(x); return u.s;
}
__device__ __forceinline__ float b2f(bf16 v){ return __bfloat162float(v); }

// ---------- W swizzle: fragment-ordered bf16 -----------------------------------
// layout: flat = (((kb*NB + nb)*8 + h)*64 + lane)*8 + j
//   k = kb*32 + (lane>>4)*8 + j ; n = nb*128 + h*16 + (lane&15)
__global__ __launch_bounds__(256) void k_swzw(const float* __restrict__ W,
                                              bf16* __restrict__ o,
                                              int K, int Kpad, int N, int NB){
    int total = Kpad*N;
    for (int f = blockIdx.x*256 + threadIdx.x; f < total; f += gridDim.x*256){
        int j = f & 7, lane = (f>>3) & 63, h = (f>>9) & 7, u = f>>12;
        int nb = u % NB, kb = u / NB;
        int k = kb*32 + ((lane>>4)<<3) + j;
        int n = nb*128 + h*16 + (lane&15);
        float v = (k < K) ? W[(size_t)k*N + n] : 0.f;
        o[f] = __float2bfloat16(v);
    }
}

// ---------- valid mask ----------------------------------------------------------
__global__ __launch_bounds__(256) void k_valid(const float* __restrict__ src,
                                               const float* __restrict__ srcn,
                                               float* __restrict__ vm){
    int m = blockIdx.x; int b = m / NN, n = m % NN;
    const float* row = (n == 0) ? src + (size_t)b*SS
                                : srcn + ((size_t)b*LL + (n-1))*SS;
    float s = 0.f;
    for (int i = threadIdx.x; i < SS; i += 256) s += fabsf(row[i]);
    __shared__ float red[256];
    red[threadIdx.x] = s; __syncthreads();
    for (int st = 128; st > 0; st >>= 1){
        if (threadIdx.x < st) red[threadIdx.x] += red[threadIdx.x + st];
        __syncthreads();
    }
    if (threadIdx.x == 0) vm[m] = (red[0] > 0.f) ? 1.f : 0.f;
}

// ---------- epilogue modes ------------------------------------------------------
#define EPI_NONE 0
#define EPI_BN_LEAKY 1
#define EPI_RES 2
#define EPI_GELU 3

// ---------- generic MFMA GEMM: A bf16 [*, lda] @ Wsw -> 128x128 tiles ----------
__global__ __launch_bounds__(256) void k_mgemm(
    const unsigned short* __restrict__ A, int lda,
    const unsigned short* __restrict__ Wsw, int NB, int nKb,
    const float* __restrict__ bias, const float* __restrict__ bng,
    const float* __restrict__ bnb, const float* __restrict__ res,
    int res_stride, int mode,
    float* __restrict__ out, bf16* __restrict__ outbf, int ldo)
{
    __shared__ short8 As[512];      // 128 rows x 32 k, fragment-swizzled
    int row0 = blockIdx.x*128;
    int nb = blockIdx.y;
    int tid = threadIdx.x;
    int wv = tid>>6, lane = tid&63;
    int wr = wv>>1, wc = wv&1;
    int quad = lane>>4, l15 = lane&15;

    f32x4 zz = {0.f,0.f,0.f,0.f};
    f32x4 acc[4][4];
    #pragma unroll
    for (int i=0;i<4;i++){ acc[i][0]=zz; acc[i][1]=zz; acc[i][2]=zz; acc[i][3]=zz; }

    int m0 = tid>>2, k8 = tid&3;
    int m1 = m0 + 64;
    int dst0 = (m0>>4)*64 + (m0&15) + (k8<<4);
    int dst1 = (m1>>4)*64 + (m1&15) + (k8<<4);
    const short8* W8 = (const short8*)Wsw;

    for (int kb = 0; kb < nKb; kb++){
        int k0 = kb*32;
        uint4 v0 = *(const uint4*)(A + (size_t)(row0+m0)*lda + k0 + k8*8);
        uint4 v1 = *(const uint4*)(A + (size_t)(row0+m1)*lda + k0 + k8*8);
        short8 bfr[4];
        #pragma unroll
        for (int h = 0; h < 4; h++)
            bfr[h] = W8[((size_t)(kb*NB + nb)*8 + wc*4 + h)*64 + lane];
        __syncthreads();
        ((uint4*)As)[dst0] = v0;
        ((uint4*)As)[dst1] = v1;
        __syncthreads();
        #pragma unroll
        for (int i = 0; i < 4; i++){
            short8 af = As[(wr*4+i)*64 + lane];
            #pragma unroll
            for (int h = 0; h < 4; h++)
                acc[i][h] = __builtin_amdgcn_mfma_f32_16x16x32_bf16(af, bfr[h], acc[i][h], 0,0,0);
        }
    }

    const float inv = rsqrtf(1.f + 1e-5f);
    #pragma unroll
    for (int i = 0; i < 4; i++){
        int rbase = row0 + wr*64 + i*16 + quad*4;
        #pragma unroll
        for (int h = 0; h < 4; h++){
            int c = nb*128 + wc*64 + h*16 + l15;
            float bi = bias ? bias[c] : 0.f;
            #pragma unroll
            for (int reg = 0; reg < 4; reg++){
                int r = rbase + reg;
                float y = acc[i][h][reg] + bi;
                if (mode == EPI_BN_LEAKY)      y = lrelu(y*(bng[c]*inv) + bnb[c]);
                else if (mode == EPI_RES)      y += res[(size_t)r*res_stride + c];
                else if (mode == EPI_GELU)     y = gelu_tanh(y);
                if (out)   out[(size_t)r*ldo + c] = y;
                if (outbf) outbf[(size_t)r*ldo + c] = __float2bfloat16(y);
            }
        }
    }
}

// ---------- enc1 MFMA GEMM: A = concat(source,source_neighbor) fp32, K=877 -----
__global__ __launch_bounds__(256) void k_mgemm1(
    const float* __restrict__ src, const float* __restrict__ srcn,
    const unsigned short* __restrict__ Wsw,
    const float* __restrict__ bias, const float* __restrict__ bng,
    const float* __restrict__ bnb, bf16* __restrict__ outbf)
{
    __shared__ short8 As[512];
    int row0 = blockIdx.x*128;
    int nb = blockIdx.y;           // NB = 4 (N=512)
    int tid = threadIdx.x;
    int wv = tid>>6, lane = tid&63;
    int wr = wv>>1, wc = wv&1;
    int quad = lane>>4, l15 = lane&15;

    f32x4 zz = {0.f,0.f,0.f,0.f};
    f32x4 acc[4][4];
    #pragma unroll
    for (int i=0;i<4;i++){ acc[i][0]=zz; acc[i][1]=zz; acc[i][2]=zz; acc[i][3]=zz; }

    int m0 = tid>>2, k8 = tid&3;
    int m1 = m0 + 64;
    int dst0 = (m0>>4)*64 + (m0&15) + (k8<<4);
    int dst1 = (m1>>4)*64 + (m1&15) + (k8<<4);
    // row base pointers (hoisted)
    int mg0 = row0 + m0, b0 = mg0/NN, n0 = mg0%NN;
    int mg1 = row0 + m1, b1 = mg1/NN, n1 = mg1%NN;
    const float* r0 = (n0==0) ? src + (size_t)b0*SS : srcn + ((size_t)b0*LL + (n0-1))*SS;
    const float* r1 = (n1==0) ? src + (size_t)b1*SS : srcn + ((size_t)b1*LL + (n1-1))*SS;
    const short8* W8 = (const short8*)Wsw;
    const int nKb = KP1/32;        // 28

    for (int kb = 0; kb < nKb; kb++){
        int kbase = kb*32 + k8*8;
        short8 p0, p1;
        #pragma unroll
        for (int e = 0; e < 8; e++){
            int k = kbase + e;
            p0[e] = f2b((k < SS) ? r0[k] : 0.f);
            p1[e] = f2b((k < SS) ? r1[k] : 0.f);
        }
        short8 bfr[4];
        #pragma unroll
        for (int h = 0; h < 4; h++)
            bfr[h] = W8[((size_t)(kb*4 + nb)*8 + wc*4 + h)*64 + lane];
        __syncthreads();
        As[dst0] = p0;
        As[dst1] = p1;
        __syncthreads();
        #pragma unroll
        for (int i = 0; i < 4; i++){
            short8 af = As[(wr*4+i)*64 + lane];
            #pragma unroll
            for (int h = 0; h < 4; h++)
                acc[i][h] = __builtin_amdgcn_mfma_f32_16x16x32_bf16(af, bfr[h], acc[i][h], 0,0,0);
        }
    }

    const float inv = rsqrtf(1.f + 1e-5f);
    #pragma unroll
    for (int i = 0; i < 4; i++){
        int rbase = row0 + wr*64 + i*16 + quad*4;
        #pragma unroll
        for (int h = 0; h < 4; h++){
            int c = nb*128 + wc*64 + h*16 + l15;
            float bi = bias[c], g = bng[c]*inv, b2 = bnb[c];
            #pragma unroll
            for (int reg = 0; reg < 4; reg++){
                float y = lrelu((acc[i][h][reg] + bi)*g + b2);
                outbf[(size_t)(rbase+reg)*D2 + c] = __float2bfloat16(y);
            }
        }
    }
}

// ---------- pred head MFMA: per (row-block, t): (128x256)@(256x128) + reduce ---
__global__ __launch_bounds__(256) void k_pred_mfma(
    const unsigned short* __restrict__ feat,   // bf16 [4096][256]
    const unsigned short* __restrict__ Wsw,    // [t*8+kb][h][lane][j]
    const float* __restrict__ b1, const float* __restrict__ bg,
    const float* __restrict__ bb, const float* __restrict__ w2,
    float* __restrict__ outp)
{
    __shared__ short8 As[512];
    int row0 = blockIdx.x*128;
    int t = blockIdx.y;
    int tid = threadIdx.x;
    int wv = tid>>6, lane = tid&63;
    int quad = lane>>4, l15 = lane&15;

    f32x4 zz = {0.f,0.f,0.f,0.f};
    f32x4 acc[2][8];
    #pragma unroll
    for (int i=0;i<2;i++)
        #pragma unroll
        for (int h=0;h<8;h++) acc[i][h] = zz;

    int m0 = tid>>2, k8 = tid&3;
    int m1 = m0 + 64;
    int dst0 = (m0>>4)*64 + (m0&15) + (k8<<4);
    int dst1 = (m1>>4)*64 + (m1&15) + (k8<<4);
    const short8* W8 = (const short8*)Wsw;

    for (int kb = 0; kb < 8; kb++){
        int k0 = kb*32;
        uint4 v0 = *(const uint4*)(feat + (size_t)(row0+m0)*DD + k0 + k8*8);
        uint4 v1 = *(const uint4*)(feat + (size_t)(row0+m1)*DD + k0 + k8*8);
        short8 bfr[8];
        #pragma unroll
        for (int h = 0; h < 8; h++)
            bfr[h] = W8[((size_t)(t*8 + kb)*8 + h)*64 + lane];
        __syncthreads();
        ((uint4*)As)[dst0] = v0;
        ((uint4*)As)[dst1] = v1;
        __syncthreads();
        #pragma unroll
        for (int i = 0; i < 2; i++){
            short8 af = As[(wv*2+i)*64 + lane];
            #pragma unroll
            for (int h = 0; h < 8; h++)
                acc[i][h] = __builtin_amdgcn_mfma_f32_16x16x32_bf16(af, bfr[h], acc[i][h], 0,0,0);
        }
    }

    const float inv = rsqrtf(1.f + 1e-5f);
    #pragma unroll
    for (int i = 0; i < 2; i++){
        #pragma unroll
        for (int reg = 0; reg < 4; reg++){
            float p = 0.f;
            #pragma unroll
            for (int h = 0; h < 8; h++){
                int hc = h*16 + l15;
                float y = (acc[i][h][reg] + b1[t*HH+hc])*(bg[t*HH+hc]*inv) + bb[t*HH+hc];
                p += lrelu(y) * w2[t*HH+hc];
            }
            p += __shfl_xor(p, 1);
            p += __shfl_xor(p, 2);
            p += __shfl_xor(p, 4);
            p += __shfl_xor(p, 8);
            if (l15 == 0){
                int r = row0 + wv*32 + i*16 + quad*4 + reg;
                outp[(size_t)r*TT + t] = p;
            }
        }
    }
}

// ---------- role + class tokens (fp32 in-place) + bf16 copy --------------------
__global__ __launch_bounds__(256) void k_rolecls(const float* __restrict__ tokc,
                                                 const float* __restrict__ tokn1,
                                                 const float* __restrict__ tokn2,
                                                 const float* __restrict__ cell_tokens,
                                                 const float* __restrict__ cell_inf,
                                                 const float* __restrict__ vm,
                                                 float* __restrict__ fo,
                                                 bf16* __restrict__ fobf){
    int m = blockIdx.x, d = threadIdx.x;
    int n = m % NN;
    float v = vm[m];
    const float* role = (n == 0) ? tokc : (n <= 4 ? tokn1 : tokn2);
    float cl = 0.f;
    #pragma unroll
    for (int c = 0; c < 13; c++)
        cl += cell_inf[(size_t)m*13 + c] * cell_tokens[c*DD + d];
    float y = fo[(size_t)m*DD + d] + (role[d] + cl) * v;
    fo[(size_t)m*DD + d] = y;
    fobf[(size_t)m*DD + d] = __float2bfloat16(y);
}

// ---------- LN helpers ----------------------------------------------------------
__device__ __forceinline__ float blksum(float v, float* red){
    int t = threadIdx.x;
    red[t] = v; __syncthreads();
    for (int s = 128; s > 0; s >>= 1){
        if (t < s) red[t] += red[t+s];
        __syncthreads();
    }
    float r = red[0]; __syncthreads();
    return r;
}

// t0 -> LN(proj)->relu -> fo1 (fp32) ; LN(fo1, attn) -> hn (bf16)
__global__ __launch_bounds__(256) void k_lnchain(const float* __restrict__ in,
                                                 const float* __restrict__ g1, const float* __restrict__ b1,
                                                 const float* __restrict__ g2, const float* __restrict__ b2,
                                                 float* __restrict__ fo1, bf16* __restrict__ hn){
    __shared__ float red[256];
    int m = blockIdx.x, d = threadIdx.x;
    float x = in[(size_t)m*DD + d];
    float mu = blksum(x, red) * (1.f/256.f);
    float dx = x - mu;
    float var = blksum(dx*dx, red) * (1.f/256.f);
    float y = dx * rsqrtf(var + 1e-5f) * g1[d] + b1[d];
    y = fmaxf(y, 0.f);
    fo1[(size_t)m*DD + d] = y;
    float mu2 = blksum(y, red) * (1.f/256.f);
    float dy = y - mu2;
    float var2 = blksum(dy*dy, red) * (1.f/256.f);
    hn[(size_t)m*DD + d] = __float2bfloat16(dy * rsqrtf(var2 + 1e-5f) * g2[d] + b2[d]);
}

__global__ __launch_bounds__(256) void k_ln(const float* __restrict__ in,
                                            const float* __restrict__ g, const float* __restrict__ b,
                                            bf16* __restrict__ out){
    __shared__ float red[256];
    int m = blockIdx.x, d = threadIdx.x;
    float x = in[(size_t)m*DD + d];
    float mu = blksum(x, red) * (1.f/256.f);
    float dx = x - mu;
    float var = blksum(dx*dx, red) * (1.f/256.f);
    out[(size_t)m*DD + d] = __float2bfloat16(dx * rsqrtf(var + 1e-5f) * g[d] + b[d]);
}

// ---------- attention (query token 0 only), bf16 in/out -------------------------
__global__ __launch_bounds__(256) void k_attn(const bf16* __restrict__ q,
                                              const bf16* __restrict__ k,
                                              const bf16* __restrict__ v,
                                              const float* __restrict__ vm,
                                              bf16* __restrict__ o){
    int b = blockIdx.x, t = threadIdx.x;
    __shared__ float ks[NN][DD];
    __shared__ float vs[NN][DD];
    __shared__ float qs[DD];
    __shared__ float sc[4][NN];
    __shared__ float val[NN];
    qs[t] = b2f(q[(size_t)b*DD + t]);
    for (int j = 0; j < NN; j++){
        ks[j][t] = b2f(k[((size_t)b*NN + j)*DD + t]);
        vs[j][t] = b2f(v[((size_t)b*NN + j)*DD + t]);
    }
    if (t < NN) val[t] = vm[b*NN + t];
    __syncthreads();
    if (t < 4*NN){
        int h = t / NN, j = t % NN;
        float s = 0.f;
        for (int d = 0; d < 64; d++) s += qs[h*64+d] * ks[j][h*64+d];
        s *= 0.125f;
        if (!(val[j] > 0.f)) s = -1e9f;
        sc[h][j] = s;
    }
    __syncthreads();
    if (t < 4){
        float mx = -1e30f;
        for (int j = 0; j < NN; j++) mx = fmaxf(mx, sc[t][j]);
        float den = 0.f;
        for (int j = 0; j < NN; j++){ float e = expf(sc[t][j]-mx); sc[t][j] = e; den += e; }
        float iv = 1.f/den;
        for (int j = 0; j < NN; j++) sc[t][j] *= iv;
    }
    __syncthreads();
    int h = t >> 6;
    float acc = 0.f;
    for (int j = 0; j < NN; j++) acc += sc[h][j] * vs[j][t];
    o[(size_t)b*DD + t] = __float2bfloat16(acc);
}

extern "C" void kernel_launch(void* const* d_in, const int* in_sizes, int n_in,
                              void* d_out, int out_size, void* d_ws, size_t ws_size,
                              hipStream_t stream) {
    const float* src      = (const float*)d_in[0];
    const float* srcn     = (const float*)d_in[1];
    const float* cell_inf = (const float*)d_in[2];
    const float* enc_w1   = (const float*)d_in[3];
    const float* enc_b1   = (const float*)d_in[4];
    const float* bn1g     = (const float*)d_in[5];
    const float* bn1b     = (const float*)d_in[6];
    const float* enc_w2   = (const float*)d_in[7];
    const float* enc_b2   = (const float*)d_in[8];
    const float* bn2g     = (const float*)d_in[9];
    const float* bn2b     = (const float*)d_in[10];
    const float* proj_w   = (const float*)d_in[11];
    const float* proj_b   = (const float*)d_in[12];
    const float* pln_g    = (const float*)d_in[13];
    const float* pln_b    = (const float*)d_in[14];
    const float* aln_g    = (const float*)d_in[15];
    const float* aln_b    = (const float*)d_in[16];
    const float* wq       = (const float*)d_in[17];
    const float* wk       = (const float*)d_in[18];
    const float* wv       = (const float*)d_in[19];
    const float* wo       = (const float*)d_in[20];
    const float* wo_b     = (const float*)d_in[21];
    const float* fln_g    = (const float*)d_in[22];
    const float* fln_b    = (const float*)d_in[23];
    const float* ff_w1    = (const float*)d_in[24];
    const float* ff_b1    = (const float*)d_in[25];
    const float* ff_w2    = (const float*)d_in[26];
    const float* ff_b2    = (const float*)d_in[27];
    const float* tokc     = (const float*)d_in[28];
    const float* tokn1    = (const float*)d_in[29];
    const float* tokn2    = (const float*)d_in[30];
    const float* cell_tok = (const float*)d_in[31];
    const float* pw1      = (const float*)d_in[32];
    const float* pb1      = (const float*)d_in[33];
    const float* pbg      = (const float*)d_in[34];
    const float* pbb      = (const float*)d_in[35];
    const float* pw2      = (const float*)d_in[36];
    float* out            = (float*)d_out;

    char* base = (char*)d_ws;
    size_t off = 0;
    auto alloc = [&](size_t bytes)->char*{
        char* p = base + off;
        off += (bytes + 255) & ~(size_t)255;
        return p;
    };
    // swizzled weights (bf16)
    bf16* sw_enc1 = (bf16*)alloc((size_t)KP1*D2*2);
    bf16* sw_enc2 = (bf16*)alloc((size_t)D2*DD*2);
    bf16* sw_proj = (bf16*)alloc((size_t)DD*DD*2);
    bf16* sw_wq   = (bf16*)alloc((size_t)DD*DD*2);
    bf16* sw_wk   = (bf16*)alloc((size_t)DD*DD*2);
    bf16* sw_wv   = (bf16*)alloc((size_t)DD*DD*2);
    bf16* sw_wo   = (bf16*)alloc((size_t)DD*DD*2);
    bf16* sw_ff1  = (bf16*)alloc((size_t)DD*D2*2);
    bf16* sw_ff2  = (bf16*)alloc((size_t)D2*DD*2);
    bf16* sw_pred = (bf16*)alloc((size_t)TT*DD*HH*2);
    // activations
    float* vm    = (float*)alloc((size_t)MM*4);
    bf16* h1bf   = (bf16*)alloc((size_t)MM*D2*2);     // later: kbbf+vbbf alias
    float* fo    = (float*)alloc((size_t)MM*DD*4);
    bf16* fobf   = (bf16*)alloc((size_t)MM*DD*2);
    float* t0    = (float*)alloc((size_t)MM*DD*4);
    bf16* hnbf   = (bf16*)alloc((size_t)MM*DD*2);
    bf16* qbf    = (bf16*)alloc((size_t)BB*DD*2);
    bf16* obbf   = (bf16*)alloc((size_t)BB*DD*2);
    float* fo2   = (float*)alloc((size_t)BB*DD*4);
    bf16* hn2bf  = (bf16*)alloc((size_t)BB*DD*2);
    bf16* g1bf   = (bf16*)alloc((size_t)BB*D2*2);
    bf16* featbf = (bf16*)alloc((size_t)BB*DD*2);
    // aliases into h1bf region (dead after enc2)
    bf16* kbbf = h1bf;
    bf16* vbbf = h1bf + (size_t)MM*DD;

    dim3 blk(256);

    // weight swizzles
    k_swzw<<<512, blk, 0, stream>>>(enc_w1, sw_enc1, SS, KP1, D2, 4);
    k_swzw<<<512, blk, 0, stream>>>(enc_w2, sw_enc2, D2, D2, DD, 2);
    k_swzw<<<256, blk, 0, stream>>>(proj_w, sw_proj, DD, DD, DD, 2);
    k_swzw<<<256, blk, 0, stream>>>(wq,     sw_wq,   DD, DD, DD, 2);
    k_swzw<<<256, blk, 0, stream>>>(wk,     sw_wk,   DD, DD, DD, 2);
    k_swzw<<<256, blk, 0, stream>>>(wv,     sw_wv,   DD, DD, DD, 2);
    k_swzw<<<256, blk, 0, stream>>>(wo,     sw_wo,   DD, DD, DD, 2);
    k_swzw<<<256, blk, 0, stream>>>(ff_w1,  sw_ff1,  DD, DD, D2, 4);
    k_swzw<<<256, blk, 0, stream>>>(ff_w2,  sw_ff2,  D2, D2, DD, 2);
    k_swzw<<<2048, blk, 0, stream>>>(pw1,   sw_pred, TT*DD, TT*DD, HH, 1);

    k_valid<<<MM, blk, 0, stream>>>(src, srcn, vm);

    // enc1: (M,877)@(877,512) -> bn1 -> leaky -> h1bf
    k_mgemm1<<<dim3(MM/128, 4), blk, 0, stream>>>(src, srcn, (const unsigned short*)sw_enc1,
        enc_b1, bn1g, bn1b, h1bf);
    // enc2: (M,512)@(512,256) -> bn2 -> leaky -> fo (fp32)
    k_mgemm<<<dim3(MM/128, 2), blk, 0, stream>>>((const unsigned short*)h1bf, D2,
        (const unsigned short*)sw_enc2, 2, 16, enc_b2, bn2g, bn2b,
        nullptr, 0, EPI_BN_LEAKY, fo, nullptr, DD);
    // + (role + class)*vm ; emit bf16 copy
    k_rolecls<<<MM, blk, 0, stream>>>(tokc, tokn1, tokn2, cell_tok, cell_inf, vm, fo, fobf);
    // proj -> t0 (fp32)
    k_mgemm<<<dim3(MM/128, 2), blk, 0, stream>>>((const unsigned short*)fobf, DD,
        (const unsigned short*)sw_proj, 2, 8, proj_b, nullptr, nullptr,
        nullptr, 0, EPI_NONE, t0, nullptr, DD);
    // LN->relu->fo1 (into fo), LN->hnbf
    k_lnchain<<<MM, blk, 0, stream>>>(t0, pln_g, pln_b, aln_g, aln_b, fo, hnbf);
    // k, v over all rows; q token-0 rows only (lda = 9*256)
    k_mgemm<<<dim3(MM/128, 2), blk, 0, stream>>>((const unsigned short*)hnbf, DD,
        (const unsigned short*)sw_wk, 2, 8, nullptr, nullptr, nullptr,
        nullptr, 0, EPI_NONE, nullptr, kbbf, DD);
    k_mgemm<<<dim3(MM/128, 2), blk, 0, stream>>>((const unsigned short*)hnbf, DD,
        (const unsigned short*)sw_wv, 2, 8, nullptr, nullptr, nullptr,
        nullptr, 0, EPI_NONE, nullptr, vbbf, DD);
    k_mgemm<<<dim3(BB/128, 2), blk, 0, stream>>>((const unsigned short*)hnbf, NN*DD,
        (const unsigned short*)sw_wq, 2, 8, nullptr, nullptr, nullptr,
        nullptr, 0, EPI_NONE, nullptr, qbf, DD);
    // attention
    k_attn<<<BB, blk, 0, stream>>>(qbf, kbbf, vbbf, vm, obbf);
    // fo2 = fo1[token0] + o@wo + wo_b   (res stride = 9*256 over fo)
    k_mgemm<<<dim3(BB/128, 2), blk, 0, stream>>>((const unsigned short*)obbf, DD,
        (const unsigned short*)sw_wo, 2, 8, wo_b, nullptr, nullptr,
        fo, NN*DD, EPI_RES, fo2, nullptr, DD);
    // hn2 = ln(fo2)
    k_ln<<<BB, blk, 0, stream>>>(fo2, fln_g, fln_b, hn2bf);
    // g1 = gelu(hn2@ff_w1 + b1)
    k_mgemm<<<dim3(BB/128, 4), blk, 0, stream>>>((const unsigned short*)hn2bf, DD,
        (const unsigned short*)sw_ff1, 4, 8, ff_b1, nullptr, nullptr,
        nullptr, 0, EPI_GELU, nullptr, g1bf, D2);
    // feat = fo2 + g1@ff_w2 + b2
    k_mgemm<<<dim3(BB/128, 2), blk, 0, stream>>>((const unsigned short*)g1bf, D2,
        (const unsigned short*)sw_ff2, 2, 16, ff_b2, nullptr, nullptr,
        fo2, DD, EPI_RES, nullptr, featbf, DD);
    // pred head -> out (fp32)
    k_pred_mfma<<<dim3(BB/128, TT), blk, 0, stream>>>((const unsigned short*)featbf,
        (const unsigned short*)sw_pred, pb1, pbg, pbb, pw2, out);
}

// Round 4
// 757.756 us; speedup vs baseline: 2.8626x; 1.3282x over previous
//
#include <hip/hip_runtime.h>
#include <hip/hip_bf16.h>
#include <math.h>

typedef __hip_bfloat16 bf16;
typedef __attribute__((ext_vector_type(8))) short short8;
typedef __attribute__((ext_vector_type(4))) float f32x4;

#define BB 4096
#define LL 8
#define NN 9
#define SS 877
#define DD 256
#define D2 512
#define TT 137
#define HH 128
#define MM (BB*NN)   // 36864
#define KP1 896      // 877 padded to mult of 32

__device__ __forceinline__ float lrelu(float x){ return x > 0.f ? x : 0.01f*x; }
__device__ __forceinline__ float gelu_tanh(float x){
    float x3 = x*x*x;
    float t = tanhf(0.7978845608028654f*(x + 0.044715f*x3));
    return 0.5f*x*(1.f + t);
}
__device__ __forceinline__ short f2b(float x){
    union { bf16 h; short s; } u; u.h = __float2bfloat16(x); return u.s;
}
__device__ __forceinline__ float b2f(bf16 v){ return __bfloat162float(v); }

// ---------- fused swizzle of ALL weights into fragment order -------------------
// layout per weight: flat = (((kb*NB + nb)*8 + h)*64 + lane)*8 + j
//   k = kb*32 + (lane>>4)*8 + j ; n = nb*128 + h*16 + (lane&15)
struct SwzD { const float* src; unsigned short* dst; int K; int N; int NB; long long base; };
struct SwzTab { SwzD d[10]; long long total; };

__global__ __launch_bounds__(256) void k_swzall(SwzTab tab){
    for (long long f0 = (long long)blockIdx.x*256 + threadIdx.x; f0 < tab.total;
         f0 += (long long)gridDim.x*256){
        int di = 0;
        #pragma unroll
        for (int q = 1; q < 10; q++) if (f0 >= tab.d[q].base) di = q;
        const SwzD dd = tab.d[di];
        long long f = f0 - dd.base;
        int j = (int)(f & 7); int lane = (int)((f>>3)&63); int h = (int)((f>>9)&7);
        long long u = f>>12;
        int nb = (int)(u % dd.NB), kb = (int)(u / dd.NB);
        int k = kb*32 + ((lane>>4)<<3) + j;
        int n = nb*128 + h*16 + (lane&15);
        float v = (k < dd.K) ? dd.src[(size_t)k*dd.N + n] : 0.f;
        dd.dst[f] = (unsigned short)f2b(v);
    }
}

// ---------- prep: valid mask + x -> bf16 [MM][896] (zero-padded) ---------------
__global__ __launch_bounds__(256) void k_prep(const float* __restrict__ src,
                                              const float* __restrict__ srcn,
                                              float* __restrict__ vm,
                                              unsigned short* __restrict__ xbf){
    int m = blockIdx.x; int b = m / NN, n = m % NN;
    const float* row = (n == 0) ? src + (size_t)b*SS
                                : srcn + ((size_t)b*LL + (n-1))*SS;
    unsigned short* orow = xbf + (size_t)m*KP1;
    float s = 0.f;
    for (int i = threadIdx.x; i < KP1; i += 256){
        float v = (i < SS) ? row[i] : 0.f;
        s += fabsf(v);
        orow[i] = (unsigned short)f2b(v);
    }
    #pragma unroll
    for (int o = 32; o > 0; o >>= 1) s += __shfl_xor(s, o);
    __shared__ float part[4];
    if ((threadIdx.x & 63) == 0) part[threadIdx.x>>6] = s;
    __syncthreads();
    if (threadIdx.x == 0)
        vm[m] = ((part[0]+part[1]+part[2]+part[3]) > 0.f) ? 1.f : 0.f;
}

// ---------- epilogue modes ------------------------------------------------------
#define EPI_NONE 0
#define EPI_BN_LEAKY 1
#define EPI_RES 2
#define EPI_GELU 3

// ---------- generic MFMA GEMM: A bf16 [*, lda] @ Wsw -> 128x128 tiles ----------
__global__ __launch_bounds__(256) void k_mgemm(
    const unsigned short* __restrict__ A, int lda,
    const unsigned short* __restrict__ Wsw, int NB, int nKb,
    const float* __restrict__ bias, const float* __restrict__ bng,
    const float* __restrict__ bnb, const float* __restrict__ res,
    int res_stride, int mode,
    float* __restrict__ out, bf16* __restrict__ outbf, int ldo)
{
    __shared__ short8 As[512];      // 128 rows x 32 k, fragment-swizzled
    int row0 = blockIdx.x*128;
    int nb = blockIdx.y;
    int tid = threadIdx.x;
    int wv = tid>>6, lane = tid&63;
    int wr = wv>>1, wc = wv&1;
    int quad = lane>>4, l15 = lane&15;

    f32x4 zz = {0.f,0.f,0.f,0.f};
    f32x4 acc[4][4];
    #pragma unroll
    for (int i=0;i<4;i++){ acc[i][0]=zz; acc[i][1]=zz; acc[i][2]=zz; acc[i][3]=zz; }

    int m0 = tid>>2, k8 = tid&3;
    int m1 = m0 + 64;
    int dst0 = (m0>>4)*64 + (m0&15) + (k8<<4);
    int dst1 = (m1>>4)*64 + (m1&15) + (k8<<4);
    const short8* W8 = (const short8*)Wsw;

    for (int kb = 0; kb < nKb; kb++){
        int k0 = kb*32;
        uint4 v0 = *(const uint4*)(A + (size_t)(row0+m0)*lda + k0 + k8*8);
        uint4 v1 = *(const uint4*)(A + (size_t)(row0+m1)*lda + k0 + k8*8);
        short8 bfr[4];
        #pragma unroll
        for (int h = 0; h < 4; h++)
            bfr[h] = W8[((size_t)(kb*NB + nb)*8 + wc*4 + h)*64 + lane];
        __syncthreads();
        ((uint4*)As)[dst0] = v0;
        ((uint4*)As)[dst1] = v1;
        __syncthreads();
        #pragma unroll
        for (int i = 0; i < 4; i++){
            short8 af = As[(wr*4+i)*64 + lane];
            #pragma unroll
            for (int h = 0; h < 4; h++)
                acc[i][h] = __builtin_amdgcn_mfma_f32_16x16x32_bf16(af, bfr[h], acc[i][h], 0,0,0);
        }
    }

    const float inv = rsqrtf(1.f + 1e-5f);
    #pragma unroll
    for (int i = 0; i < 4; i++){
        int rbase = row0 + wr*64 + i*16 + quad*4;
        #pragma unroll
        for (int h = 0; h < 4; h++){
            int c = nb*128 + wc*64 + h*16 + l15;
            float bi = bias ? bias[c] : 0.f;
            #pragma unroll
            for (int reg = 0; reg < 4; reg++){
                int r = rbase + reg;
                float y = acc[i][h][reg] + bi;
                if (mode == EPI_BN_LEAKY)      y = lrelu(y*(bng[c]*inv) + bnb[c]);
                else if (mode == EPI_RES)      y += res[(size_t)r*res_stride + c];
                else if (mode == EPI_GELU)     y = gelu_tanh(y);
                if (out)   out[(size_t)r*ldo + c] = y;
                if (outbf) outbf[(size_t)r*ldo + c] = __float2bfloat16(y);
            }
        }
    }
}

// ---------- pred head MFMA: per (row-block, t): (128x256)@(256x128) + reduce ---
__global__ __launch_bounds__(256) void k_pred_mfma(
    const unsigned short* __restrict__ feat,   // bf16 [4096][256]
    const unsigned short* __restrict__ Wsw,    // [(t*8+kb)][h][lane][j]
    const float* __restrict__ b1, const float* __restrict__ bg,
    const float* __restrict__ bb, const float* __restrict__ w2,
    float* __restrict__ outp)
{
    __shared__ short8 As[512];
    int row0 = blockIdx.x*128;
    int t = blockIdx.y;
    int tid = threadIdx.x;
    int wv = tid>>6, lane = tid&63;
    int quad = lane>>4, l15 = lane&15;

    const float inv = rsqrtf(1.f + 1e-5f);
    float b1v[8], bgv[8], bbv[8], w2v[8];
    #pragma unroll
    for (int h = 0; h < 8; h++){
        int hc = t*HH + h*16 + l15;
        b1v[h] = b1[hc]; bgv[h] = bg[hc]*inv; bbv[h] = bb[hc]; w2v[h] = w2[hc];
    }

    f32x4 zz = {0.f,0.f,0.f,0.f};
    f32x4 acc[2][8];
    #pragma unroll
    for (int i=0;i<2;i++)
        #pragma unroll
        for (int h=0;h<8;h++) acc[i][h] = zz;

    int m0 = tid>>2, k8 = tid&3;
    int m1 = m0 + 64;
    int dst0 = (m0>>4)*64 + (m0&15) + (k8<<4);
    int dst1 = (m1>>4)*64 + (m1&15) + (k8<<4);
    const short8* W8 = (const short8*)Wsw;

    for (int kb = 0; kb < 8; kb++){
        int k0 = kb*32;
        uint4 v0 = *(const uint4*)(feat + (size_t)(row0+m0)*DD + k0 + k8*8);
        uint4 v1 = *(const uint4*)(feat + (size_t)(row0+m1)*DD + k0 + k8*8);
        short8 bfr[8];
        #pragma unroll
        for (int h = 0; h < 8; h++)
            bfr[h] = W8[((size_t)(t*8 + kb)*8 + h)*64 + lane];
        __syncthreads();
        ((uint4*)As)[dst0] = v0;
        ((uint4*)As)[dst1] = v1;
        __syncthreads();
        #pragma unroll
        for (int i = 0; i < 2; i++){
            short8 af = As[(wv*2+i)*64 + lane];
            #pragma unroll
            for (int h = 0; h < 8; h++)
                acc[i][h] = __builtin_amdgcn_mfma_f32_16x16x32_bf16(af, bfr[h], acc[i][h], 0,0,0);
        }
    }

    #pragma unroll
    for (int i = 0; i < 2; i++){
        #pragma unroll
        for (int reg = 0; reg < 4; reg++){
            float p = 0.f;
            #pragma unroll
            for (int h = 0; h < 8; h++){
                float y = (acc[i][h][reg] + b1v[h])*bgv[h] + bbv[h];
                p += lrelu(y) * w2v[h];
            }
            p += __shfl_xor(p, 1);
            p += __shfl_xor(p, 2);
            p += __shfl_xor(p, 4);
            p += __shfl_xor(p, 8);
            if (l15 == 0){
                int r = row0 + wv*32 + i*16 + quad*4 + reg;
                outp[(size_t)r*TT + t] = p;
            }
        }
    }
}

// ---------- role + class tokens (fp32 in-place) + bf16 copy --------------------
__global__ __launch_bounds__(256) void k_rolecls(const float* __restrict__ tokc,
                                                 const float* __restrict__ tokn1,
                                                 const float* __restrict__ tokn2,
                                                 const float* __restrict__ cell_tokens,
                                                 const float* __restrict__ cell_inf,
                                                 const float* __restrict__ vm,
                                                 float* __restrict__ fo,
                                                 bf16* __restrict__ fobf){
    int m = blockIdx.x, d = threadIdx.x;
    int n = m % NN;
    float v = vm[m];
    const float* role = (n == 0) ? tokc : (n <= 4 ? tokn1 : tokn2);
    float cl = 0.f;
    #pragma unroll
    for (int c = 0; c < 13; c++)
        cl += cell_inf[(size_t)m*13 + c] * cell_tokens[c*DD + d];
    float y = fo[(size_t)m*DD + d] + (role[d] + cl) * v;
    fo[(size_t)m*DD + d] = y;
    fobf[(size_t)m*DD + d] = __float2bfloat16(y);
}

// ---------- LN helpers (wave shfl + 2 barriers) --------------------------------
__device__ __forceinline__ float blksum(float v, float* part){
    #pragma unroll
    for (int o = 32; o > 0; o >>= 1) v += __shfl_xor(v, o);
    __syncthreads();
    if ((threadIdx.x & 63) == 0) part[threadIdx.x>>6] = v;
    __syncthreads();
    return part[0]+part[1]+part[2]+part[3];
}

// t0 -> LN(proj)->relu -> fo1 (fp32) ; LN(fo1, attn) -> hn (bf16)
__global__ __launch_bounds__(256) void k_lnchain(const float* __restrict__ in,
                                                 const float* __restrict__ g1, const float* __restrict__ b1,
                                                 const float* __restrict__ g2, const float* __restrict__ b2,
                                                 float* __restrict__ fo1, bf16* __restrict__ hn){
    __shared__ float part[4];
    int m = blockIdx.x, d = threadIdx.x;
    float x = in[(size_t)m*DD + d];
    float mu = blksum(x, part) * (1.f/256.f);
    float dx = x - mu;
    float var = blksum(dx*dx, part) * (1.f/256.f);
    float y = dx * rsqrtf(var + 1e-5f) * g1[d] + b1[d];
    y = fmaxf(y, 0.f);
    fo1[(size_t)m*DD + d] = y;
    float mu2 = blksum(y, part) * (1.f/256.f);
    float dy = y - mu2;
    float var2 = blksum(dy*dy, part) * (1.f/256.f);
    hn[(size_t)m*DD + d] = __float2bfloat16(dy * rsqrtf(var2 + 1e-5f) * g2[d] + b2[d]);
}

__global__ __launch_bounds__(256) void k_ln(const float* __restrict__ in,
                                            const float* __restrict__ g, const float* __restrict__ b,
                                            bf16* __restrict__ out){
    __shared__ float part[4];
    int m = blockIdx.x, d = threadIdx.x;
    float x = in[(size_t)m*DD + d];
    float mu = blksum(x, part) * (1.f/256.f);
    float dx = x - mu;
    float var = blksum(dx*dx, part) * (1.f/256.f);
    out[(size_t)m*DD + d] = __float2bfloat16(dx * rsqrtf(var + 1e-5f) * g[d] + b[d]);
}

// ---------- attention (query token 0 only), bf16 in/out -------------------------
__global__ __launch_bounds__(256) void k_attn(const bf16* __restrict__ q,
                                              const bf16* __restrict__ k,
                                              const bf16* __restrict__ v,
                                              const float* __restrict__ vm,
                                              bf16* __restrict__ o){
    int b = blockIdx.x, t = threadIdx.x;
    __shared__ float ks[NN][DD];
    __shared__ float vs[NN][DD];
    __shared__ float qs[DD];
    __shared__ float sc[4][NN];
    __shared__ float val[NN];
    qs[t] = b2f(q[(size_t)b*DD + t]);
    for (int j = 0; j < NN; j++){
        ks[j][t] = b2f(k[((size_t)b*NN + j)*DD + t]);
        vs[j][t] = b2f(v[((size_t)b*NN + j)*DD + t]);
    }
    if (t < NN) val[t] = vm[b*NN + t];
    __syncthreads();
    if (t < 4*NN){
        int h = t / NN, j = t % NN;
        float s = 0.f;
        for (int d = 0; d < 64; d++) s += qs[h*64+d] * ks[j][h*64+d];
        s *= 0.125f;
        if (!(val[j] > 0.f)) s = -1e9f;
        sc[h][j] = s;
    }
    __syncthreads();
    if (t < 4){
        float mx = -1e30f;
        for (int j = 0; j < NN; j++) mx = fmaxf(mx, sc[t][j]);
        float den = 0.f;
        for (int j = 0; j < NN; j++){ float e = expf(sc[t][j]-mx); sc[t][j] = e; den += e; }
        float iv = 1.f/den;
        for (int j = 0; j < NN; j++) sc[t][j] *= iv;
    }
    __syncthreads();
    int h = t >> 6;
    float acc = 0.f;
    for (int j = 0; j < NN; j++) acc += sc[h][j] * vs[j][t];
    o[(size_t)b*DD + t] = __float2bfloat16(acc);
}

extern "C" void kernel_launch(void* const* d_in, const int* in_sizes, int n_in,
                              void* d_out, int out_size, void* d_ws, size_t ws_size,
                              hipStream_t stream) {
    const float* src      = (const float*)d_in[0];
    const float* srcn     = (const float*)d_in[1];
    const float* cell_inf = (const float*)d_in[2];
    const float* enc_w1   = (const float*)d_in[3];
    const float* enc_b1   = (const float*)d_in[4];
    const float* bn1g     = (const float*)d_in[5];
    const float* bn1b     = (const float*)d_in[6];
    const float* enc_w2   = (const float*)d_in[7];
    const float* enc_b2   = (const float*)d_in[8];
    const float* bn2g     = (const float*)d_in[9];
    const float* bn2b     = (const float*)d_in[10];
    const float* proj_w   = (const float*)d_in[11];
    const float* proj_b   = (const float*)d_in[12];
    const float* pln_g    = (const float*)d_in[13];
    const float* pln_b    = (const float*)d_in[14];
    const float* aln_g    = (const float*)d_in[15];
    const float* aln_b    = (const float*)d_in[16];
    const float* wq       = (const float*)d_in[17];
    const float* wk       = (const float*)d_in[18];
    const float* wv       = (const float*)d_in[19];
    const float* wo       = (const float*)d_in[20];
    const float* wo_b     = (const float*)d_in[21];
    const float* fln_g    = (const float*)d_in[22];
    const float* fln_b    = (const float*)d_in[23];
    const float* ff_w1    = (const float*)d_in[24];
    const float* ff_b1    = (const float*)d_in[25];
    const float* ff_w2    = (const float*)d_in[26];
    const float* ff_b2    = (const float*)d_in[27];
    const float* tokc     = (const float*)d_in[28];
    const float* tokn1    = (const float*)d_in[29];
    const float* tokn2    = (const float*)d_in[30];
    const float* cell_tok = (const float*)d_in[31];
    const float* pw1      = (const float*)d_in[32];
    const float* pb1      = (const float*)d_in[33];
    const float* pbg      = (const float*)d_in[34];
    const float* pbb      = (const float*)d_in[35];
    const float* pw2      = (const float*)d_in[36];
    float* out            = (float*)d_out;

    char* base = (char*)d_ws;
    size_t off = 0;
    auto alloc = [&](size_t bytes)->char*{
        char* p = base + off;
        off += (bytes + 255) & ~(size_t)255;
        return p;
    };
    // swizzled weights (bf16)
    bf16* sw_enc1 = (bf16*)alloc((size_t)KP1*D2*2);
    bf16* sw_enc2 = (bf16*)alloc((size_t)D2*DD*2);
    bf16* sw_proj = (bf16*)alloc((size_t)DD*DD*2);
    bf16* sw_wq   = (bf16*)alloc((size_t)DD*DD*2);
    bf16* sw_wk   = (bf16*)alloc((size_t)DD*DD*2);
    bf16* sw_wv   = (bf16*)alloc((size_t)DD*DD*2);
    bf16* sw_wo   = (bf16*)alloc((size_t)DD*DD*2);
    bf16* sw_ff1  = (bf16*)alloc((size_t)DD*D2*2);
    bf16* sw_ff2  = (bf16*)alloc((size_t)D2*DD*2);
    bf16* sw_pred = (bf16*)alloc((size_t)TT*DD*HH*2);
    // activations (with aliasing)
    float* vm    = (float*)alloc((size_t)MM*4);
    char*  xreg  = alloc((size_t)MM*KP1*2);           // xbf; later fo + fobf
    bf16*  h1bf  = (bf16*)alloc((size_t)MM*D2*2);     // later: kbbf+vbbf
    float* t0    = (float*)alloc((size_t)MM*DD*4);
    bf16*  hnbf  = (bf16*)alloc((size_t)MM*DD*2);
    bf16*  qbf   = (bf16*)alloc((size_t)BB*DD*2);
    bf16*  obbf  = (bf16*)alloc((size_t)BB*DD*2);
    float* fo2   = (float*)alloc((size_t)BB*DD*4);
    bf16*  hn2bf = (bf16*)alloc((size_t)BB*DD*2);
    bf16*  g1bf  = (bf16*)alloc((size_t)BB*D2*2);
    bf16*  featbf= (bf16*)alloc((size_t)BB*DD*2);
    // aliases
    unsigned short* xbf = (unsigned short*)xreg;                  // dead after enc1
    float* fo   = (float*)xreg;                                   // MM*DD fp32
    bf16*  fobf = (bf16*)(xreg + (size_t)MM*DD*4);                // MM*DD bf16
    bf16* kbbf = h1bf;                                            // after enc2
    bf16* vbbf = h1bf + (size_t)MM*DD;

    dim3 blk(256);

    // fused weight swizzle
    SwzTab tab;
    long long cum = 0;
    auto mk = [&](int slot, const float* s, bf16* d, int K, int Kpad, int N, int NB){
        tab.d[slot] = SwzD{ s, (unsigned short*)d, K, N, NB, cum };
        cum += (long long)Kpad*N;
    };
    mk(0, enc_w1, sw_enc1, SS, KP1, D2, 4);
    mk(1, enc_w2, sw_enc2, D2, D2, DD, 2);
    mk(2, proj_w, sw_proj, DD, DD, DD, 2);
    mk(3, wq,     sw_wq,   DD, DD, DD, 2);
    mk(4, wk,     sw_wk,   DD, DD, DD, 2);
    mk(5, wv,     sw_wv,   DD, DD, DD, 2);
    mk(6, wo,     sw_wo,   DD, DD, DD, 2);
    mk(7, ff_w1,  sw_ff1,  DD, DD, D2, 4);
    mk(8, ff_w2,  sw_ff2,  D2, D2, DD, 2);
    mk(9, pw1,    sw_pred, TT*DD, TT*DD, HH, 1);
    tab.total = cum;
    k_swzall<<<1024, blk, 0, stream>>>(tab);

    // prep: vm + bf16 x
    k_prep<<<MM, blk, 0, stream>>>(src, srcn, vm, xbf);

    // enc1: (M,896)@(896,512) -> bn1 -> leaky -> h1bf (bf16)
    k_mgemm<<<dim3(MM/128, 4), blk, 0, stream>>>(xbf, KP1,
        (const unsigned short*)sw_enc1, 4, KP1/32, enc_b1, bn1g, bn1b,
        nullptr, 0, EPI_BN_LEAKY, nullptr, h1bf, D2);
    // enc2: (M,512)@(512,256) -> bn2 -> leaky -> fo (fp32)  [xbf now dead]
    k_mgemm<<<dim3(MM/128, 2), blk, 0, stream>>>((const unsigned short*)h1bf, D2,
        (const unsigned short*)sw_enc2, 2, 16, enc_b2, bn2g, bn2b,
        nullptr, 0, EPI_BN_LEAKY, fo, nullptr, DD);
    // + (role + class)*vm ; emit bf16 copy
    k_rolecls<<<MM, blk, 0, stream>>>(tokc, tokn1, tokn2, cell_tok, cell_inf, vm, fo, fobf);
    // proj -> t0 (fp32)
    k_mgemm<<<dim3(MM/128, 2), blk, 0, stream>>>((const unsigned short*)fobf, DD,
        (const unsigned short*)sw_proj, 2, 8, proj_b, nullptr, nullptr,
        nullptr, 0, EPI_NONE, t0, nullptr, DD);
    // LN->relu->fo1 (into fo), LN->hnbf
    k_lnchain<<<MM, blk, 0, stream>>>(t0, pln_g, pln_b, aln_g, aln_b, fo, hnbf);
    // k, v over all rows; q token-0 rows only (lda = 9*256)
    k_mgemm<<<dim3(MM/128, 2), blk, 0, stream>>>((const unsigned short*)hnbf, DD,
        (const unsigned short*)sw_wk, 2, 8, nullptr, nullptr, nullptr,
        nullptr, 0, EPI_NONE, nullptr, kbbf, DD);
    k_mgemm<<<dim3(MM/128, 2), blk, 0, stream>>>((const unsigned short*)hnbf, DD,
        (const unsigned short*)sw_wv, 2, 8, nullptr, nullptr, nullptr,
        nullptr, 0, EPI_NONE, nullptr, vbbf, DD);
    k_mgemm<<<dim3(BB/128, 2), blk, 0, stream>>>((const unsigned short*)hnbf, NN*DD,
        (const unsigned short*)sw_wq, 2, 8, nullptr, nullptr, nullptr,
        nullptr, 0, EPI_NONE, nullptr, qbf, DD);
    // attention
    k_attn<<<BB, blk, 0, stream>>>(qbf, kbbf, vbbf, vm, obbf);
    // fo2 = fo1[token0] + o@wo + wo_b   (res stride = 9*256 over fo)
    k_mgemm<<<dim3(BB/128, 2), blk, 0, stream>>>((const unsigned short*)obbf, DD,
        (const unsigned short*)sw_wo, 2, 8, wo_b, nullptr, nullptr,
        fo, NN*DD, EPI_RES, fo2, nullptr, DD);
    // hn2 = ln(fo2)
    k_ln<<<BB, blk, 0, stream>>>(fo2, fln_g, fln_b, hn2bf);
    // g1 = gelu(hn2@ff_w1 + b1)
    k_mgemm<<<dim3(BB/128, 4), blk, 0, stream>>>((const unsigned short*)hn2bf, DD,
        (const unsigned short*)sw_ff1, 4, 8, ff_b1, nullptr, nullptr,
        nullptr, 0, EPI_GELU, nullptr, g1bf, D2);
    // feat = fo2 + g1@ff_w2 + b2
    k_mgemm<<<dim3(BB/128, 2), blk, 0, stream>>>((const unsigned short*)g1bf, D2,
        (const unsigned short*)sw_ff2, 2, 16, ff_b2, nullptr, nullptr,
        fo2, DD, EPI_RES, nullptr, featbf, DD);
    // pred head -> out (fp32)
    k_pred_mfma<<<dim3(BB/128, TT), blk, 0, stream>>>((const unsigned short*)featbf,
        (const unsigned short*)sw_pred, pb1, pbg, pbb, pw2, out);
}